// Round 1
// baseline (55.358 us; speedup 1.0000x reference)
//
#include <hip/hip_runtime.h>

// Problem constants from the reference.
#define CCL_N 16384
#define CCL_D 2048
#define CCL_C 1000

// One block per row: dist[i] = clip( sum_j (x[i,j] - w[labels[i],j])^2 ).
// D = 2048 floats = 512 float4; 256 threads -> 2 float4 per thread, fully
// coalesced on x. w rows (8 KiB each, 8 MiB total) are gathered and live in
// L2/L3 after first touch.
__global__ __launch_bounds__(256) void ccl_row_kernel(const float* __restrict__ x,
                                                      const int* __restrict__ labels,
                                                      const float* __restrict__ w,
                                                      float* __restrict__ partials) {
    const int row = blockIdx.x;
    const int t = threadIdx.x;
    const int l = labels[row];

    const float4* __restrict__ xr = reinterpret_cast<const float4*>(x + (size_t)row * CCL_D);
    const float4* __restrict__ wr = reinterpret_cast<const float4*>(w + (size_t)l * CCL_D);

    float acc = 0.0f;
#pragma unroll
    for (int k = 0; k < 2; ++k) {
        const float4 xv = xr[t + k * 256];
        const float4 wv = wr[t + k * 256];
        const float d0 = xv.x - wv.x;
        const float d1 = xv.y - wv.y;
        const float d2 = xv.z - wv.z;
        const float d3 = xv.w - wv.w;
        acc += d0 * d0 + d1 * d1 + d2 * d2 + d3 * d3;
    }

    // Wave-64 butterfly-free down-reduce.
#pragma unroll
    for (int off = 32; off > 0; off >>= 1)
        acc += __shfl_down(acc, off, 64);

    __shared__ float wsum[4];
    const int lane = t & 63;
    const int wid = t >> 6;
    if (lane == 0) wsum[wid] = acc;
    __syncthreads();

    if (t == 0) {
        float s = wsum[0] + wsum[1] + wsum[2] + wsum[3];
        // clip(dist, 1e-12, 1e12) per the reference (applied per row, pre-sum).
        s = fminf(fmaxf(s, 1e-12f), 1e12f);
        partials[row] = s;
    }
}

// Single-block final reduce of the 16384 per-row partials -> mean.
__global__ __launch_bounds__(256) void ccl_reduce_kernel(const float* __restrict__ partials,
                                                         float* __restrict__ out) {
    const int t = threadIdx.x;
    float acc = 0.0f;
    for (int i = t; i < CCL_N; i += 256)
        acc += partials[i];

#pragma unroll
    for (int off = 32; off > 0; off >>= 1)
        acc += __shfl_down(acc, off, 64);

    __shared__ float wsum[4];
    const int lane = t & 63;
    const int wid = t >> 6;
    if (lane == 0) wsum[wid] = acc;
    __syncthreads();

    if (t == 0)
        out[0] = (wsum[0] + wsum[1] + wsum[2] + wsum[3]) * (1.0f / (float)CCL_N);
}

extern "C" void kernel_launch(void* const* d_in, const int* in_sizes, int n_in,
                              void* d_out, int out_size, void* d_ws, size_t ws_size,
                              hipStream_t stream) {
    const float* x = (const float*)d_in[0];       // [N, D] fp32
    const int* labels = (const int*)d_in[1];      // [N] int32
    const float* w = (const float*)d_in[2];       // [C, D] fp32
    float* out = (float*)d_out;                   // scalar fp32
    float* partials = (float*)d_ws;               // N floats = 64 KiB scratch

    ccl_row_kernel<<<CCL_N, 256, 0, stream>>>(x, labels, w, partials);
    ccl_reduce_kernel<<<1, 256, 0, stream>>>(partials, out);
}

// Round 2
// 40.821 us; speedup vs baseline: 1.3561x; 1.3561x over previous
//
#include <hip/hip_runtime.h>

// Problem constants from the reference.
#define CCL_N 16384
#define CCL_D 2048
#define CCL_C 1000

// One row per WAVE: 64 lanes x 8 float4 = 2048 floats = one row.
// Block = 256 threads = 4 waves = 4 consecutive rows (keeps x reads in a
// contiguous 32 KiB chunk per block for DRAM page locality).
// All 16 loads (8 x + 8 w) are issued before any arithmetic -> 256 B/lane
// in flight, deep MLP. 4 independent accumulators break the dep chain.
__global__ __launch_bounds__(256) void ccl_row_kernel(const float* __restrict__ x,
                                                      const int* __restrict__ labels,
                                                      const float* __restrict__ w,
                                                      float* __restrict__ blockpart) {
    const int t = threadIdx.x;
    const int lane = t & 63;
    const int wid = t >> 6;
    const int row = blockIdx.x * 4 + wid;

    const int l = labels[row];  // wave-uniform broadcast load

    const float4* __restrict__ xr = reinterpret_cast<const float4*>(x + (size_t)row * CCL_D);
    const float4* __restrict__ wr = reinterpret_cast<const float4*>(w + (size_t)l * CCL_D);

    float4 xv[8], wv[8];
#pragma unroll
    for (int k = 0; k < 8; ++k) xv[k] = xr[lane + 64 * k];
#pragma unroll
    for (int k = 0; k < 8; ++k) wv[k] = wr[lane + 64 * k];

    float a0 = 0.f, a1 = 0.f, a2 = 0.f, a3 = 0.f;
#pragma unroll
    for (int k = 0; k < 8; ++k) {
        const float d0 = xv[k].x - wv[k].x;
        const float d1 = xv[k].y - wv[k].y;
        const float d2 = xv[k].z - wv[k].z;
        const float d3 = xv[k].w - wv[k].w;
        a0 += d0 * d0;
        a1 += d1 * d1;
        a2 += d2 * d2;
        a3 += d3 * d3;
    }
    float acc = (a0 + a1) + (a2 + a3);

    // Per-wave reduce only -- no block sync on this path.
#pragma unroll
    for (int off = 32; off > 0; off >>= 1)
        acc += __shfl_down(acc, off, 64);

    __shared__ float wsum[4];
    if (lane == 0)
        wsum[wid] = fminf(fmaxf(acc, 1e-12f), 1e12f);  // per-row clip, per reference
    __syncthreads();

    if (t == 0)
        blockpart[blockIdx.x] = (wsum[0] + wsum[1]) + (wsum[2] + wsum[3]);
}

// Single-block final reduce of 4096 per-block partials -> mean over N rows.
__global__ __launch_bounds__(256) void ccl_reduce_kernel(const float* __restrict__ part,
                                                         float* __restrict__ out) {
    const int t = threadIdx.x;
    const float4* __restrict__ p4 = reinterpret_cast<const float4*>(part);

    float acc = 0.f;
#pragma unroll
    for (int k = 0; k < 4; ++k) {
        const float4 v = p4[t + 256 * k];  // 4096 floats = 1024 float4
        acc += (v.x + v.y) + (v.z + v.w);
    }

#pragma unroll
    for (int off = 32; off > 0; off >>= 1)
        acc += __shfl_down(acc, off, 64);

    __shared__ float wsum[4];
    const int lane = t & 63;
    const int wid = t >> 6;
    if (lane == 0) wsum[wid] = acc;
    __syncthreads();

    if (t == 0)
        out[0] = ((wsum[0] + wsum[1]) + (wsum[2] + wsum[3])) * (1.0f / (float)CCL_N);
}

extern "C" void kernel_launch(void* const* d_in, const int* in_sizes, int n_in,
                              void* d_out, int out_size, void* d_ws, size_t ws_size,
                              hipStream_t stream) {
    const float* x = (const float*)d_in[0];       // [N, D] fp32
    const int* labels = (const int*)d_in[1];      // [N] int32
    const float* w = (const float*)d_in[2];       // [C, D] fp32
    float* out = (float*)d_out;                   // scalar fp32
    float* blockpart = (float*)d_ws;              // 4096 floats = 16 KiB scratch

    ccl_row_kernel<<<CCL_N / 4, 256, 0, stream>>>(x, labels, w, blockpart);
    ccl_reduce_kernel<<<1, 256, 0, stream>>>(blockpart, out);
}

// Round 4
// 36.685 us; speedup vs baseline: 1.5090x; 1.1127x over previous
//
#include <hip/hip_runtime.h>

// Problem constants from the reference.
#define CCL_N 16384
#define CCL_D 2048
#define CCL_C 1000

#define CCL_GRID 1024                       // persistent blocks
#define CCL_ITERS (CCL_N / (4 * CCL_GRID))  // 4 rows per wave

// Native vector type so __builtin_nontemporal_load accepts it.
typedef float f32x4 __attribute__((ext_vector_type(4)));

// One row per WAVE (64 lanes x 8 float4 = 2048 floats), 4 waves/block,
// grid-stride over CCL_ITERS row-groups so each wave handles 4 rows.
//  - x is streamed exactly once: nontemporal loads keep it from thrashing
//    the per-XCD L2, preserving L2 for the 8 MiB w table (16x reuse).
//  - All 16 loads of a row are issued before any arithmetic (256 B/lane
//    in flight); 4 independent accumulators break the FMA dep chain.
//  - Per-wave running sum across iterations; a single LDS combine + one
//    store per block at the end (1024 partials total).
__global__ __launch_bounds__(256) void ccl_row_kernel(const float* __restrict__ x,
                                                      const int* __restrict__ labels,
                                                      const float* __restrict__ w,
                                                      float* __restrict__ blockpart) {
    const int t = threadIdx.x;
    const int lane = t & 63;
    const int wid = t >> 6;

    float wave_acc = 0.0f;  // lane 0 carries the running block-row sum

#pragma unroll
    for (int g = 0; g < CCL_ITERS; ++g) {
        const int row = (blockIdx.x * CCL_ITERS + g) * 4 + wid;
        const int l = labels[row];  // wave-uniform broadcast load

        const f32x4* __restrict__ xr =
            reinterpret_cast<const f32x4*>(x + (size_t)row * CCL_D);
        const f32x4* __restrict__ wr =
            reinterpret_cast<const f32x4*>(w + (size_t)l * CCL_D);

        f32x4 xv[8], wv[8];
#pragma unroll
        for (int k = 0; k < 8; ++k) xv[k] = __builtin_nontemporal_load(&xr[lane + 64 * k]);
#pragma unroll
        for (int k = 0; k < 8; ++k) wv[k] = wr[lane + 64 * k];

        float a0 = 0.f, a1 = 0.f, a2 = 0.f, a3 = 0.f;
#pragma unroll
        for (int k = 0; k < 8; ++k) {
            const f32x4 d = xv[k] - wv[k];
            a0 += d.x * d.x;
            a1 += d.y * d.y;
            a2 += d.z * d.z;
            a3 += d.w * d.w;
        }
        float acc = (a0 + a1) + (a2 + a3);

        // Per-wave reduce; no block sync inside the loop.
#pragma unroll
        for (int off = 32; off > 0; off >>= 1)
            acc += __shfl_down(acc, off, 64);

        // Per-row clip per the reference, then accumulate (lane 0 only is valid).
        wave_acc += fminf(fmaxf(acc, 1e-12f), 1e12f);
    }

    __shared__ float wsum[4];
    if (lane == 0) wsum[wid] = wave_acc;
    __syncthreads();

    if (t == 0)
        blockpart[blockIdx.x] = (wsum[0] + wsum[1]) + (wsum[2] + wsum[3]);
}

// Single-block final reduce of 1024 per-block partials -> mean over N rows.
__global__ __launch_bounds__(256) void ccl_reduce_kernel(const float* __restrict__ part,
                                                         float* __restrict__ out) {
    const int t = threadIdx.x;
    const f32x4 v = reinterpret_cast<const f32x4*>(part)[t];  // 1024 floats = 256 f32x4
    float acc = (v.x + v.y) + (v.z + v.w);

#pragma unroll
    for (int off = 32; off > 0; off >>= 1)
        acc += __shfl_down(acc, off, 64);

    __shared__ float wsum[4];
    const int lane = t & 63;
    const int wid = t >> 6;
    if (lane == 0) wsum[wid] = acc;
    __syncthreads();

    if (t == 0)
        out[0] = ((wsum[0] + wsum[1]) + (wsum[2] + wsum[3])) * (1.0f / (float)CCL_N);
}

extern "C" void kernel_launch(void* const* d_in, const int* in_sizes, int n_in,
                              void* d_out, int out_size, void* d_ws, size_t ws_size,
                              hipStream_t stream) {
    const float* x = (const float*)d_in[0];       // [N, D] fp32
    const int* labels = (const int*)d_in[1];      // [N] int32
    const float* w = (const float*)d_in[2];       // [C, D] fp32
    float* out = (float*)d_out;                   // scalar fp32
    float* blockpart = (float*)d_ws;              // 1024 floats = 4 KiB scratch

    ccl_row_kernel<<<CCL_GRID, 256, 0, stream>>>(x, labels, w, blockpart);
    ccl_reduce_kernel<<<1, 256, 0, stream>>>(blockpart, out);
}